// Round 4
// baseline (100.113 us; speedup 1.0000x reference)
//
#include <hip/hip_runtime.h>
#include <hip/hip_fp16.h>

#define DIM 256
#define NN  384

typedef _Float16 v2h __attribute__((ext_vector_type(2)));

__device__ __forceinline__ float fdot2f(__half2 a, __half2 b, float c) {
    // v_dot2_f32_f16: fp16 pair dot-product, fp32 accumulate
    return __builtin_amdgcn_fdot2(__builtin_bit_cast(v2h, a),
                                  __builtin_bit_cast(v2h, b), c, false);
}

// packed relu: max(a, 0) lane-wise on fp16 pair -> v_pk_max_f16
__device__ __forceinline__ __half2 relu2(__half2 a) {
    v2h av = __builtin_bit_cast(v2h, a);
#if __has_builtin(__builtin_elementwise_max)
    v2h zv = {(_Float16)0.0f, (_Float16)0.0f};
    v2h rv = __builtin_elementwise_max(av, zv);
#else
    v2h rv;
    rv.x = av.x > (_Float16)0.0f ? av.x : (_Float16)0.0f;
    rv.y = av.y > (_Float16)0.0f ? av.y : (_Float16)0.0f;
#endif
    return __builtin_bit_cast(__half2, rv);
}

// ---------------- K0: transpose Wx [e][d] -> WxT [d][e]; pack Wi/Ws fp16 ---
__global__ __launch_bounds__(256) void k_transpose(const float* __restrict__ W,
                                                   float* __restrict__ WT,
                                                   const float* __restrict__ Wi,
                                                   const float* __restrict__ Ws,
                                                   __half* __restrict__ wih,
                                                   __half* __restrict__ wsh) {
    __shared__ float t[32][33];
    const int bx = blockIdx.x & 7, by = blockIdx.x >> 3;
    const int tx = threadIdx.x & 31, ty = threadIdx.x >> 5; // ty 0..7
#pragma unroll
    for (int k = 0; k < 4; k++) {
        const int r = ty + k * 8;
        t[r][tx] = W[(by * 32 + r) * DIM + bx * 32 + tx];
    }
    if (blockIdx.x == 0) {
        wih[threadIdx.x] = __float2half(Wi[threadIdx.x]);
        wsh[threadIdx.x] = __float2half(Ws[threadIdx.x]);
    }
    __syncthreads();
#pragma unroll
    for (int k = 0; k < 4; k++) {
        const int r = ty + k * 8;
        WT[(bx * 32 + r) * DIM + by * 32 + tx] = t[tx][r];
    }
}

// ---------------- K1: xp = x @ Wx^T + bx ; emit fp16 xp and xp+bi ----------
// PR=6 rows/block -> 1536/6 = 256 blocks = exactly 1 block/CU (no straggler;
// was 1.5/CU with a 2:1 tail at PR=4) and WxT L2 traffic 96 -> 64 MB.
// Latency fix (round-3 theory): the old 4-float lookahead gave only ~64 cy
// of cover vs ~200-300 cy L2 latency -> ~5 us latency-bound. Now a full
// 16-d chunk (16 regs) is prefetched one chunk ahead; compute per chunk is
// PR*16 fmaf ~ 192 cy, covering most of the latency.
// x rows stay in LDS (uniform-address broadcast reads, ~free).
#define PR 6
__global__ __launch_bounds__(256) void k_proj(const float* __restrict__ x,
                                              const float* __restrict__ WxT,
                                              const float* __restrict__ bx,
                                              const float* __restrict__ bi,
                                              __half* __restrict__ xph,
                                              __half* __restrict__ xpbh) {
    __shared__ float xs[PR][DIM];
    const int row0 = blockIdx.x * PR;
    const int e = threadIdx.x;
    const float* xr = x + (size_t)row0 * DIM;
#pragma unroll
    for (int k = 0; k < PR; k++) xs[k][e] = xr[k * DIM + e];

    float acc[PR];
    const float b0 = bx[e];
#pragma unroll
    for (int r = 0; r < PR; r++) acc[r] = b0;

    // prefetch chunk 0 (d = 0..15) while LDS staging settles
    float wb[16];
#pragma unroll
    for (int q = 0; q < 16; q++) wb[q] = WxT[q * DIM + e];

    __syncthreads();

#pragma unroll 1
    for (int c = 0; c < 16; c++) {
        float wn[16];
        const int dn = ((c + 1) & 15) * 16; // wraps to 0 on last iter (harmless)
#pragma unroll
        for (int q = 0; q < 16; q++) wn[q] = WxT[(dn + q) * DIM + e];
        const int d0 = c * 16;
#pragma unroll
        for (int q4 = 0; q4 < 4; q4++) {
#pragma unroll
            for (int r = 0; r < PR; r++) {
                const float4 xv = *(const float4*)&xs[r][d0 + q4 * 4]; // LDS bcast
                acc[r] = fmaf(xv.x, wb[q4 * 4 + 0], acc[r]);
                acc[r] = fmaf(xv.y, wb[q4 * 4 + 1], acc[r]);
                acc[r] = fmaf(xv.z, wb[q4 * 4 + 2], acc[r]);
                acc[r] = fmaf(xv.w, wb[q4 * 4 + 3], acc[r]);
            }
        }
#pragma unroll
        for (int q = 0; q < 16; q++) wb[q] = wn[q]; // rotate (all static idx)
    }
    const float biv = bi[e];
#pragma unroll
    for (int r = 0; r < PR; r++) {
        xph [(size_t)(row0 + r) * DIM + e] = __float2half(acc[r]);
        xpbh[(size_t)(row0 + r) * DIM + e] = __float2half(acc[r] + biv);
    }
}

// ---------------- K2: out[b,i,j] = sigmoid( sum_d relu(...)*Ws + bs ) ------
// 32x32 pair tile/block; 2x2 reg tile/thread (i in {il,il+16}, j in {jl,jl+16}).
// 576 blocks = 2.25/CU: staging of one block overlaps compute of another
// (round-3 lesson: the 48x48 1-block/CU variant serializes its stage phase
// and measured ~2 us slower overall). Packed-f16 math: 2 inst per
// (output,d) = the VALU floor for this algorithm. d-loop fully unrolled.
#define LDW 264  // halfs per LDS row: 256 + 8 pad (528 B, 16B-divisible)
__global__ __launch_bounds__(256) void k_main(const __half* __restrict__ xpbh,
                                              const __half* __restrict__ xph,
                                              const float* __restrict__ inc,
                                              const __half* __restrict__ wih,
                                              const __half* __restrict__ wsh,
                                              const float* __restrict__ bs,
                                              float* __restrict__ out) {
    __shared__ __half xi[32][LDW]; // xp[i] + bi
    __shared__ __half xj[32][LDW]; // xp[j]
    const int blk = blockIdx.x;           // 576 = 4 * 12 * 12
    const int jt = blk % 12;
    const int it = (blk / 12) % 12;
    const int b  = blk / 144;
    const int i0 = it * 32, j0 = jt * 32;
    const int t  = threadIdx.x;
    const int il = t >> 4, jl = t & 15;   // 16 x 16 threads

    // issue inc loads FIRST: latency hides under LDS staging + barrier
    const float* incp = inc + ((size_t)(b * NN) + i0 + il) * NN + j0 + jl;
    const float inc00 = incp[0];
    const float inc01 = incp[16];
    const float inc10 = incp[16 * NN];
    const float inc11 = incp[16 * NN + 16];
    const float bsv = bs[0];

    const __half* gi = xpbh + (size_t)(b * NN + i0) * DIM;
    const __half* gj = xph  + (size_t)(b * NN + j0) * DIM;
    for (int idx = t; idx < 32 * 32; idx += 256) { // 32 rows x 32 16B-chunks
        const int r = idx >> 5, c = (idx & 31) * 8;
        *(float4*)(&xi[r][c]) = *(const float4*)(gi + r * DIM + c);
        *(float4*)(&xj[r][c]) = *(const float4*)(gj + r * DIM + c);
    }
    __syncthreads();

    const __half2 i00p = __float2half2_rn(inc00);
    const __half2 i01p = __float2half2_rn(inc01);
    const __half2 i10p = __float2half2_rn(inc10);
    const __half2 i11p = __float2half2_rn(inc11);
    // fold bs into the accumulator init (kills 4 epilogue adds)
    float a00 = bsv, a01 = bsv, a10 = bsv, a11 = bsv;

    const __half2* wih2 = (const __half2*)wih;
    const __half2* wsh2 = (const __half2*)wsh;

    union F4H { float4 f; __half2 h[4]; };
#pragma unroll
    for (int d = 0; d < DIM; d += 8) {
        F4H hi0, hi1, hj0, hj1;
        hi0.f = *(const float4*)&xi[il][d];
        hi1.f = *(const float4*)&xi[il + 16][d];
        hj0.f = *(const float4*)&xj[jl][d];
        hj1.f = *(const float4*)&xj[jl + 16][d];
#pragma unroll
        for (int k2 = 0; k2 < 4; k2++) {
            const __half2 wi2 = wih2[(d >> 1) + k2]; // uniform -> s_load
            const __half2 ws2 = wsh2[(d >> 1) + k2]; // uniform -> s_load
            __half2 s00 = __hadd2(hi0.h[k2], hj0.h[k2]);
            __half2 s01 = __hadd2(hi0.h[k2], hj1.h[k2]);
            __half2 s10 = __hadd2(hi1.h[k2], hj0.h[k2]);
            __half2 s11 = __hadd2(hi1.h[k2], hj1.h[k2]);
            s00 = __hfma2(i00p, wi2, s00);
            s01 = __hfma2(i01p, wi2, s01);
            s10 = __hfma2(i10p, wi2, s10);
            s11 = __hfma2(i11p, wi2, s11);
            s00 = relu2(s00);
            s01 = relu2(s01);
            s10 = relu2(s10);
            s11 = relu2(s11);
            a00 = fdot2f(s00, ws2, a00);
            a01 = fdot2f(s01, ws2, a01);
            a10 = fdot2f(s10, ws2, a10);
            a11 = fdot2f(s11, ws2, a11);
        }
    }
    float* op = out + ((size_t)(b * NN) + i0 + il) * NN + j0 + jl;
    op[0]            = 1.f / (1.f + __expf(-a00));
    op[16]           = 1.f / (1.f + __expf(-a01));
    op[16 * NN]      = 1.f / (1.f + __expf(-a10));
    op[16 * NN + 16] = 1.f / (1.f + __expf(-a11));
}

extern "C" void kernel_launch(void* const* d_in, const int* in_sizes, int n_in,
                              void* d_out, int out_size, void* d_ws, size_t ws_size,
                              hipStream_t stream) {
    const float* x   = (const float*)d_in[0]; // [B,N,DIM]
    const float* inc = (const float*)d_in[1]; // [B,N,N]
    const float* Wx  = (const float*)d_in[2]; // [DIM,DIM]
    const float* bx  = (const float*)d_in[3]; // [DIM]
    const float* Wi  = (const float*)d_in[4]; // [DIM]
    const float* bi  = (const float*)d_in[5]; // [DIM]
    const float* Ws  = (const float*)d_in[6]; // [DIM]
    const float* bs  = (const float*)d_in[7]; // [1]
    float* out = (float*)d_out;

    char* ws = (char*)d_ws;
    float*  WxT  = (float*)ws;                          // 262,144 B
    __half* xph  = (__half*)(ws + 262144);              // 786,432 B
    __half* xpbh = (__half*)(ws + 262144 + 786432);     // 786,432 B
    __half* wih  = (__half*)(ws + 262144 + 2 * 786432); // 512 B
    __half* wsh  = (__half*)(ws + 262144 + 2 * 786432 + 512);

    k_transpose<<<64,  256, 0, stream>>>(Wx, WxT, Wi, Ws, wih, wsh);
    k_proj     <<<256, 256, 0, stream>>>(x, WxT, bx, bi, xph, xpbh);
    k_main     <<<576, 256, 0, stream>>>(xpbh, xph, inc, wih, wsh, bs, out);
}